// Round 1
// baseline (339.431 us; speedup 1.0000x reference)
//
#include <hip/hip_runtime.h>

#define D_DIM 1024
#define BM 128
#define BN 128
#define BK 64

typedef unsigned short ushort_t;
typedef __attribute__((ext_vector_type(8))) short short8;
typedef __attribute__((ext_vector_type(4))) float floatx4;

__device__ __forceinline__ unsigned short f2bf(float f) {
  unsigned u = __float_as_uint(f);
  u += 0x7FFFu + ((u >> 16) & 1u);   // round-to-nearest-even
  return (unsigned short)(u >> 16);
}

__device__ __forceinline__ void gl2lds16(const void* g, void* l) {
  __builtin_amdgcn_global_load_lds(
      (const __attribute__((address_space(1))) void*)g,
      (__attribute__((address_space(3))) void*)l, 16, 0, 0);
}

// ---------- prep: fp32 -> bf16 + per-row sum of squares (exact fp32) ----------
__global__ __launch_bounds__(256) void prep_kernel(
    const float* __restrict__ X, const float* __restrict__ S,
    ushort_t* __restrict__ Xb, ushort_t* __restrict__ Sb,
    float* __restrict__ x2, float* __restrict__ s2, int Brows) {
  int row = blockIdx.x;
  const float* src; ushort_t* dst; float* sq; int r;
  if (row < Brows) { src = X; dst = Xb; sq = x2; r = row; }
  else             { src = S; dst = Sb; sq = s2; r = row - Brows; }
  int tid = threadIdx.x;
  const float4* p = (const float4*)(src + (size_t)r * D_DIM);
  float4 v = p[tid];
  float ss = v.x * v.x + v.y * v.y + v.z * v.z + v.w * v.w;
  ushort4 o;
  o.x = f2bf(v.x); o.y = f2bf(v.y); o.z = f2bf(v.z); o.w = f2bf(v.w);
  ((ushort4*)(dst + (size_t)r * D_DIM))[tid] = o;
#pragma unroll
  for (int m = 32; m > 0; m >>= 1) ss += __shfl_xor(ss, m);
  __shared__ float ws4[4];
  if ((tid & 63) == 0) ws4[tid >> 6] = ss;
  __syncthreads();
  if (tid == 0) sq[r] = ws4[0] + ws4[1] + ws4[2] + ws4[3];
}

// ---------- fused GEMM + partial logsumexp ----------
// Block tile 128x128, BK=64, 4 waves each computing 64x64 (4x4 MFMA 16x16x32 frags).
// Partial per (row, column-block): (m, l) of logsumexp over that 128-col chunk.
__global__ __launch_bounds__(256) void gemm_lse_kernel(
    const ushort_t* __restrict__ Xb, const ushort_t* __restrict__ Sb,
    const float* __restrict__ x2, const float* __restrict__ s2,
    const float* __restrict__ g, float2* __restrict__ part, int nCB) {
  __shared__ alignas(16) ushort_t As[BM * BK];
  __shared__ alignas(16) ushort_t Bs[BN * BK];
  __shared__ float red_m[BM * 2];
  __shared__ float red_l[BM * 2];

  const int tid = threadIdx.x;
  const int w = tid >> 6, lane = tid & 63;
  const int bx = blockIdx.x, by = blockIdx.y;
  const int row0 = by * BM, col0 = bx * BN;
  const int wm = w >> 1, wn = w & 1;
  const int quad = lane >> 4, l15 = lane & 15;

  floatx4 acc[4][4];
#pragma unroll
  for (int i = 0; i < 4; i++)
#pragma unroll
    for (int j = 0; j < 4; j++) acc[i][j] = (floatx4){0.f, 0.f, 0.f, 0.f};

  // staging: each global_load_lds moves 16B/lane; wave covers 8 rows x 64 cols.
  const int ldrow = w * 8 + (lane >> 3);   // + r*32
  const int ldcol = (lane & 7) * 8;
  const ushort_t* gA = Xb + (size_t)(row0 + ldrow) * D_DIM + ldcol;
  const ushort_t* gB = Sb + (size_t)(col0 + ldrow) * D_DIM + ldcol;
  ushort_t* lA = As + (w * 8) * BK;   // wave-uniform base; HW adds lane*16B
  ushort_t* lB = Bs + (w * 8) * BK;

  for (int k0 = 0; k0 < D_DIM; k0 += BK) {
#pragma unroll
    for (int r = 0; r < 4; ++r) {
      gl2lds16(gA + (size_t)(r * 32) * D_DIM + k0, lA + r * 32 * BK);
      gl2lds16(gB + (size_t)(r * 32) * D_DIM + k0, lB + r * 32 * BK);
    }
    __syncthreads();   // drains vmcnt(0): loads complete for all waves
#pragma unroll
    for (int ks = 0; ks < 2; ++ks) {
      short8 af[4], bfv[4];
#pragma unroll
      for (int mi = 0; mi < 4; mi++)
        af[mi] = *(const short8*)&As[(wm * 64 + mi * 16 + l15) * BK + ks * 32 + quad * 8];
#pragma unroll
      for (int ni = 0; ni < 4; ni++)
        bfv[ni] = *(const short8*)&Bs[(wn * 64 + ni * 16 + l15) * BK + ks * 32 + quad * 8];
#pragma unroll
      for (int mi = 0; mi < 4; mi++)
#pragma unroll
        for (int ni = 0; ni < 4; ni++)
          acc[mi][ni] = __builtin_amdgcn_mfma_f32_16x16x32_bf16(af[mi], bfv[ni], acc[mi][ni], 0, 0, 0);
    }
    __syncthreads();   // all reads done before next stage overwrites
  }

  // ---- epilogue: dist -> z = s*dist -> per-row (m,l) over 128 cols ----
  const float sgn = -g[0];
  float x2v[4][4];
#pragma unroll
  for (int mi = 0; mi < 4; mi++)
#pragma unroll
    for (int rg = 0; rg < 4; rg++)
      x2v[mi][rg] = x2[row0 + wm * 64 + mi * 16 + quad * 4 + rg];
  float s2v[4];
#pragma unroll
  for (int ni = 0; ni < 4; ni++) s2v[ni] = s2[col0 + wn * 64 + ni * 16 + l15];

#pragma unroll
  for (int mi = 0; mi < 4; mi++) {
#pragma unroll
    for (int rg = 0; rg < 4; rg++) {
      float zv[4];
      float mr = -3.4e38f;
#pragma unroll
      for (int ni = 0; ni < 4; ni++) {
        float dist = x2v[mi][rg] + s2v[ni] - 2.f * acc[mi][ni][rg];
        dist = fmaxf(dist, 0.f);
        float z = sgn * dist;
        zv[ni] = z;
        mr = fmaxf(mr, z);
      }
      float lr = 0.f;
#pragma unroll
      for (int ni = 0; ni < 4; ni++) lr += __expf(zv[ni] - mr);
      // butterfly over the 16 lanes holding this row's columns
#pragma unroll
      for (int mask = 1; mask < 16; mask <<= 1) {
        float mo = __shfl_xor(mr, mask);
        float lo = __shfl_xor(lr, mask);
        float mn = fmaxf(mr, mo);
        lr = lr * __expf(mr - mn) + lo * __expf(mo - mn);
        mr = mn;
      }
      if (l15 == 0) {
        int rl = wm * 64 + mi * 16 + quad * 4 + rg;
        red_m[rl * 2 + wn] = mr;
        red_l[rl * 2 + wn] = lr;
      }
    }
  }
  __syncthreads();
  if (tid < BM) {
    float ma = red_m[tid * 2 + 0], la = red_l[tid * 2 + 0];
    float mb = red_m[tid * 2 + 1], lb = red_l[tid * 2 + 1];
    float mn = fmaxf(ma, mb);
    float l = la * __expf(ma - mn) + lb * __expf(mb - mn);
    part[(size_t)(row0 + tid) * nCB + bx] = make_float2(mn, l);
  }
}

// ---------- finalize: merge 128 partials per row -> output ----------
__global__ __launch_bounds__(256) void finalize_kernel(
    const float2* __restrict__ part, const float* __restrict__ g,
    float* __restrict__ out, int nCB, int Ntot) {
  int w = threadIdx.x >> 6, lane = threadIdx.x & 63;
  int row = blockIdx.x * 4 + w;
  const float2* p = part + (size_t)row * nCB;
  float2 a = p[lane];
  float2 b = p[lane + 64];
  float m = fmaxf(a.x, b.x);
  float l = a.y * __expf(a.x - m) + b.y * __expf(b.x - m);
#pragma unroll
  for (int mask = 1; mask < 64; mask <<= 1) {
    float mo = __shfl_xor(m, mask);
    float lo = __shfl_xor(l, mask);
    float mn = fmaxf(m, mo);
    l = l * __expf(m - mn) + lo * __expf(mo - mn);
    m = mn;
  }
  if (lane == 0) {
    float sgn = -g[0];
    out[row] = (m + logf(l) - logf((float)Ntot)) / sgn;
  }
}

extern "C" void kernel_launch(void* const* d_in, const int* in_sizes, int n_in,
                              void* d_out, int out_size, void* d_ws, size_t ws_size,
                              hipStream_t stream) {
  const float* X = (const float*)d_in[0];
  const float* S = (const float*)d_in[1];
  const float* g = (const float*)d_in[2];
  float* out = (float*)d_out;
  const int Bt = in_sizes[0] / D_DIM;   // 4096
  const int Nt = in_sizes[1] / D_DIM;   // 16384
  const int nCB = Nt / BN;              // 128

  char* ws = (char*)d_ws;
  size_t off = 0;
  float2* part = (float2*)(ws + off); off += (size_t)Bt * nCB * sizeof(float2); // 4 MB
  float* x2 = (float*)(ws + off);     off += (size_t)Bt * sizeof(float);
  float* s2 = (float*)(ws + off);     off += (size_t)Nt * sizeof(float);
  off = (off + 255) & ~(size_t)255;
  ushort_t* Xb = (ushort_t*)(ws + off); off += (size_t)Bt * D_DIM * sizeof(ushort_t); // 8 MB
  ushort_t* Sb = (ushort_t*)(ws + off); off += (size_t)Nt * D_DIM * sizeof(ushort_t); // 32 MB

  prep_kernel<<<Bt + Nt, 256, 0, stream>>>(X, S, Xb, Sb, x2, s2, Bt);
  dim3 grid(nCB, Bt / BM);
  gemm_lse_kernel<<<grid, 256, 0, stream>>>(Xb, Sb, x2, s2, g, part, nCB);
  finalize_kernel<<<Bt / 4, 256, 0, stream>>>(part, g, out, nCB, Nt);
}

// Round 2
// 292.476 us; speedup vs baseline: 1.1605x; 1.1605x over previous
//
#include <hip/hip_runtime.h>

#define D_DIM 1024
#define BM 128
#define BN 128
#define BK 64

typedef unsigned short ushort_t;
typedef __attribute__((ext_vector_type(8))) short short8;
typedef __attribute__((ext_vector_type(4))) float floatx4;

__device__ __forceinline__ unsigned short f2bf(float f) {
  unsigned u = __float_as_uint(f);
  u += 0x7FFFu + ((u >> 16) & 1u);   // round-to-nearest-even
  return (unsigned short)(u >> 16);
}

__device__ __forceinline__ void gl2lds16(const void* g, void* l) {
  __builtin_amdgcn_global_load_lds(
      (const __attribute__((address_space(1))) void*)g,
      (__attribute__((address_space(3))) void*)l, 16, 0, 0);
}

// ---------- prep: fp32 -> bf16 + per-row sum of squares (exact fp32) ----------
// wave-per-row: 4 outstanding float4 loads/lane, shuffle-only reduce, no barrier.
__global__ __launch_bounds__(256) void prep_kernel(
    const float* __restrict__ X, const float* __restrict__ S,
    ushort_t* __restrict__ Xb, ushort_t* __restrict__ Sb,
    float* __restrict__ x2, float* __restrict__ s2, int Brows) {
  int wid = blockIdx.x * 4 + (threadIdx.x >> 6);
  int lane = threadIdx.x & 63;
  const float* src; ushort_t* dst; float* sq; int r;
  if (wid < Brows) { src = X; dst = Xb; sq = x2; r = wid; }
  else             { src = S; dst = Sb; sq = s2; r = wid - Brows; }
  const float4* p = (const float4*)(src + (size_t)r * D_DIM);
  float4 v[4];
#pragma unroll
  for (int i = 0; i < 4; i++) v[i] = p[lane + i * 64];
  float ss = 0.f;
  ushort4* q = (ushort4*)(dst + (size_t)r * D_DIM);
#pragma unroll
  for (int i = 0; i < 4; i++) {
    ss += v[i].x * v[i].x + v[i].y * v[i].y + v[i].z * v[i].z + v[i].w * v[i].w;
    ushort4 o;
    o.x = f2bf(v[i].x); o.y = f2bf(v[i].y); o.z = f2bf(v[i].z); o.w = f2bf(v[i].w);
    q[lane + i * 64] = o;
  }
#pragma unroll
  for (int m = 32; m > 0; m >>= 1) ss += __shfl_xor(ss, m);
  if (lane == 0) sq[r] = ss;
}

// ---------- fused GEMM + partial logsumexp ----------
// 128x128 tile, BK=64, 4 waves x (64x64 via 4x4 16x16x32 bf16 MFMA frags).
// LDS XOR-swizzle: physical 16B chunk p holds logical chunk p ^ (row & 7).
// (global_load_lds dest is lane-contiguous; we permute the SOURCE per lane.)
__global__ __launch_bounds__(256) void gemm_lse_kernel(
    const ushort_t* __restrict__ Xb, const ushort_t* __restrict__ Sb,
    const float* __restrict__ x2, const float* __restrict__ s2,
    const float* __restrict__ g, float2* __restrict__ part, int nCB) {
  __shared__ alignas(16) ushort_t As[BM * BK];
  __shared__ alignas(16) ushort_t Bs[BN * BK];
  __shared__ float red_m[BM * 2];
  __shared__ float red_l[BM * 2];

  const int tid = threadIdx.x;
  const int w = tid >> 6, lane = tid & 63;
  const int bx = blockIdx.x, by = blockIdx.y;
  const int row0 = by * BM, col0 = bx * BN;
  const int wm = w >> 1, wn = w & 1;
  const int quad = lane >> 4, l15 = lane & 15;

  floatx4 acc[4][4];
#pragma unroll
  for (int i = 0; i < 4; i++)
#pragma unroll
    for (int j = 0; j < 4; j++) acc[i][j] = (floatx4){0.f, 0.f, 0.f, 0.f};

  // staging: wave covers 8 rows x 64 cols per r-step; lane (lr,p) sources
  // logical chunk p^lr so the LDS tile ends up XOR-swizzled.
  const int lr = lane >> 3;                 // row within 8-row group
  const int lc = (lane & 7) ^ lr;           // swizzled logical 16B chunk
  const int ldrow = w * 8 + lr;             // + r*32
  const int ldcol = lc * 8;                 // elements
  const ushort_t* gA = Xb + (size_t)(row0 + ldrow) * D_DIM + ldcol;
  const ushort_t* gB = Sb + (size_t)(col0 + ldrow) * D_DIM + ldcol;
  ushort_t* lA = As + (w * 8) * BK;         // wave-uniform base; HW adds lane*16B
  ushort_t* lB = Bs + (w * 8) * BK;

  const int swz = l15 & 7;                  // row&7 for fragment rows (row = ..16.. + l15)

  for (int k0 = 0; k0 < D_DIM; k0 += BK) {
#pragma unroll
    for (int r = 0; r < 4; ++r) {
      gl2lds16(gA + (size_t)(r * 32) * D_DIM + k0, lA + r * 32 * BK);
      gl2lds16(gB + (size_t)(r * 32) * D_DIM + k0, lB + r * 32 * BK);
    }
    __syncthreads();
#pragma unroll
    for (int ks = 0; ks < 2; ++ks) {
      short8 af[4], bfv[4];
#pragma unroll
      for (int mi = 0; mi < 4; mi++)
        af[mi] = *(const short8*)&As[(wm * 64 + mi * 16 + l15) * BK + (((ks * 4 + quad) ^ swz) * 8)];
#pragma unroll
      for (int ni = 0; ni < 4; ni++)
        bfv[ni] = *(const short8*)&Bs[(wn * 64 + ni * 16 + l15) * BK + (((ks * 4 + quad) ^ swz) * 8)];
#pragma unroll
      for (int mi = 0; mi < 4; mi++)
#pragma unroll
        for (int ni = 0; ni < 4; ni++)
          acc[mi][ni] = __builtin_amdgcn_mfma_f32_16x16x32_bf16(af[mi], bfv[ni], acc[mi][ni], 0, 0, 0);
    }
    __syncthreads();
  }

  // ---- epilogue: dist -> z = s*dist -> per-row (m,l) over 128 cols ----
  const float sgn = -g[0];
  float x2v[4][4];
#pragma unroll
  for (int mi = 0; mi < 4; mi++)
#pragma unroll
    for (int rg = 0; rg < 4; rg++)
      x2v[mi][rg] = x2[row0 + wm * 64 + mi * 16 + quad * 4 + rg];
  float s2v[4];
#pragma unroll
  for (int ni = 0; ni < 4; ni++) s2v[ni] = s2[col0 + wn * 64 + ni * 16 + l15];

#pragma unroll
  for (int mi = 0; mi < 4; mi++) {
#pragma unroll
    for (int rg = 0; rg < 4; rg++) {
      float zv[4];
      float mr = -3.4e38f;
#pragma unroll
      for (int ni = 0; ni < 4; ni++) {
        float dist = x2v[mi][rg] + s2v[ni] - 2.f * acc[mi][ni][rg];
        dist = fmaxf(dist, 0.f);
        float z = sgn * dist;
        zv[ni] = z;
        mr = fmaxf(mr, z);
      }
      float lr2 = 0.f;
#pragma unroll
      for (int ni = 0; ni < 4; ni++) lr2 += __expf(zv[ni] - mr);
#pragma unroll
      for (int mask = 1; mask < 16; mask <<= 1) {
        float mo = __shfl_xor(mr, mask);
        float lo = __shfl_xor(lr2, mask);
        float mn = fmaxf(mr, mo);
        lr2 = lr2 * __expf(mr - mn) + lo * __expf(mo - mn);
        mr = mn;
      }
      if (l15 == 0) {
        int rl = wm * 64 + mi * 16 + quad * 4 + rg;
        red_m[rl * 2 + wn] = mr;
        red_l[rl * 2 + wn] = lr2;
      }
    }
  }
  __syncthreads();
  if (tid < BM) {
    float ma = red_m[tid * 2 + 0], la = red_l[tid * 2 + 0];
    float mb = red_m[tid * 2 + 1], lb = red_l[tid * 2 + 1];
    float mn = fmaxf(ma, mb);
    float l = la * __expf(ma - mn) + lb * __expf(mb - mn);
    part[(size_t)(row0 + tid) * nCB + bx] = make_float2(mn, l);
  }
}

// ---------- finalize: merge 128 partials per row -> output ----------
__global__ __launch_bounds__(256) void finalize_kernel(
    const float2* __restrict__ part, const float* __restrict__ g,
    float* __restrict__ out, int nCB, int Ntot) {
  int w = threadIdx.x >> 6, lane = threadIdx.x & 63;
  int row = blockIdx.x * 4 + w;
  const float2* p = part + (size_t)row * nCB;
  float2 a = p[lane];
  float2 b = p[lane + 64];
  float m = fmaxf(a.x, b.x);
  float l = a.y * __expf(a.x - m) + b.y * __expf(b.x - m);
#pragma unroll
  for (int mask = 1; mask < 64; mask <<= 1) {
    float mo = __shfl_xor(m, mask);
    float lo = __shfl_xor(l, mask);
    float mn = fmaxf(m, mo);
    l = l * __expf(m - mn) + lo * __expf(mo - mn);
    m = mn;
  }
  if (lane == 0) {
    float sgn = -g[0];
    out[row] = (m + logf(l) - logf((float)Ntot)) / sgn;
  }
}

extern "C" void kernel_launch(void* const* d_in, const int* in_sizes, int n_in,
                              void* d_out, int out_size, void* d_ws, size_t ws_size,
                              hipStream_t stream) {
  const float* X = (const float*)d_in[0];
  const float* S = (const float*)d_in[1];
  const float* g = (const float*)d_in[2];
  float* out = (float*)d_out;
  const int Bt = in_sizes[0] / D_DIM;   // 4096
  const int Nt = in_sizes[1] / D_DIM;   // 16384
  const int nCB = Nt / BN;              // 128

  char* ws = (char*)d_ws;
  size_t off = 0;
  float2* part = (float2*)(ws + off); off += (size_t)Bt * nCB * sizeof(float2); // 4 MB
  float* x2 = (float*)(ws + off);     off += (size_t)Bt * sizeof(float);
  float* s2 = (float*)(ws + off);     off += (size_t)Nt * sizeof(float);
  off = (off + 255) & ~(size_t)255;
  ushort_t* Xb = (ushort_t*)(ws + off); off += (size_t)Bt * D_DIM * sizeof(ushort_t); // 8 MB
  ushort_t* Sb = (ushort_t*)(ws + off); off += (size_t)Nt * D_DIM * sizeof(ushort_t); // 32 MB

  prep_kernel<<<(Bt + Nt) / 4, 256, 0, stream>>>(X, S, Xb, Sb, x2, s2, Bt);
  dim3 grid(nCB, Bt / BM);
  gemm_lse_kernel<<<grid, 256, 0, stream>>>(Xb, Sb, x2, s2, g, part, nCB);
  finalize_kernel<<<Bt / 4, 256, 0, stream>>>(part, g, out, nCB, Nt);
}